// Round 7
// baseline (113.009 us; speedup 1.0000x reference)
//
#include <hip/hip_runtime.h>
#include <hip/hip_bf16.h>

// Problem constants (B, L, H, HS, OUT) = (4, 512, 768, 64, 16)
#define Bc   4
#define Lc   512
#define Hc   768
#define HSc  64
#define OUTc 16
#define Pc   131328   // L*(L+1)/2
#define KSEG 192      // K quarter (768/4)

typedef float floatx4 __attribute__((ext_vector_type(4)));

// Workspace layout (floats): q@0, k@131072, A@262144, E@294912

// Kernel 1: fused q/k projection + A/E. Grid: 512 blocks x 512 threads
// (8 waves = half x kseg), block = 4 tokens, 2 blocks/CU, 4 waves/SIMD.
// KEY CHANGE vs R4: x staged in LDS (12 KB) via vector loads; inner loop reads
// x with ds_read_b128 broadcasts instead of wave-uniform scalar s_loads
// (SMEM is out-of-order -> every use forced lgkmcnt(0) drains; that serial
// ~300cyc/load chain was the 40us. ds_read is in-order + pipelinable.)
__global__ __launch_bounds__(512, 4) void qk_proj_kernel(
    const float* __restrict__ x,
    const float* __restrict__ Wq, const float* __restrict__ bq,
    const float* __restrict__ Wk, const float* __restrict__ bk,
    const float* __restrict__ Wb, const float* __restrict__ bb,
    float* __restrict__ qws, float* __restrict__ kws,
    float* __restrict__ Aws, float* __restrict__ Ews)
{
    __shared__ alignas(16) float lds_x[4 * Hc];   // 12 KB: x[4 tokens][768]
    __shared__ float lds_p[4][4][128];            // [kseg][token][q|k]
    __shared__ float lds_c[4][128];               // combined q|k per token

    const int tid = threadIdx.x;
    const int wu  = __builtin_amdgcn_readfirstlane(tid >> 6);  // wave id 0..7
    const int half = wu & 1;                                   // 0=q, 1=k
    const int kseg = wu >> 1;                                  // 0..3
    const int col  = tid & 63;
    const int tok_base = blockIdx.x * 4;

    // Stage x slice: 4*768 floats = 768 float4, coalesced.
    {
        const float4* xg = (const float4*)(x + (size_t)tok_base * Hc);
        float4* xl = (float4*)lds_x;
        for (int i = tid; i < 768; i += 512) xl[i] = xg[i];
    }

    const float* Wp = half ? Wk : Wq;                          // wave-uniform
    const float* wp = Wp + (size_t)kseg * KSEG * HSc + col;
    const int kbase = kseg * KSEG;

    __syncthreads();

    float acc0 = 0.f, acc1 = 0.f, acc2 = 0.f, acc3 = 0.f;
    float wA[16], wB[16];

    #pragma unroll
    for (int u = 0; u < 16; ++u) wA[u] = wp[u * HSc];

    #pragma unroll 1
    for (int j0 = 0; j0 < KSEG; j0 += 32) {
        // prefetch next-16 W into wB while computing on wA
        #pragma unroll
        for (int u = 0; u < 16; ++u) wB[u] = wp[(j0 + 16 + u) * HSc];
        #pragma unroll
        for (int u4 = 0; u4 < 4; ++u4) {
            const int jj = kbase + j0 + u4 * 4;
            const float4 x0 = *(const float4*)&lds_x[0 * Hc + jj];  // broadcast
            const float4 x1 = *(const float4*)&lds_x[1 * Hc + jj];
            const float4 x2 = *(const float4*)&lds_x[2 * Hc + jj];
            const float4 x3 = *(const float4*)&lds_x[3 * Hc + jj];
            acc0 += x0.x*wA[u4*4] + x0.y*wA[u4*4+1] + x0.z*wA[u4*4+2] + x0.w*wA[u4*4+3];
            acc1 += x1.x*wA[u4*4] + x1.y*wA[u4*4+1] + x1.z*wA[u4*4+2] + x1.w*wA[u4*4+3];
            acc2 += x2.x*wA[u4*4] + x2.y*wA[u4*4+1] + x2.z*wA[u4*4+2] + x2.w*wA[u4*4+3];
            acc3 += x3.x*wA[u4*4] + x3.y*wA[u4*4+1] + x3.z*wA[u4*4+2] + x3.w*wA[u4*4+3];
        }
        // prefetch following-16 into wA while computing on wB
        if (j0 + 32 < KSEG) {
            #pragma unroll
            for (int u = 0; u < 16; ++u) wA[u] = wp[(j0 + 32 + u) * HSc];
        }
        #pragma unroll
        for (int u4 = 0; u4 < 4; ++u4) {
            const int jj = kbase + j0 + 16 + u4 * 4;
            const float4 x0 = *(const float4*)&lds_x[0 * Hc + jj];
            const float4 x1 = *(const float4*)&lds_x[1 * Hc + jj];
            const float4 x2 = *(const float4*)&lds_x[2 * Hc + jj];
            const float4 x3 = *(const float4*)&lds_x[3 * Hc + jj];
            acc0 += x0.x*wB[u4*4] + x0.y*wB[u4*4+1] + x0.z*wB[u4*4+2] + x0.w*wB[u4*4+3];
            acc1 += x1.x*wB[u4*4] + x1.y*wB[u4*4+1] + x1.z*wB[u4*4+2] + x1.w*wB[u4*4+3];
            acc2 += x2.x*wB[u4*4] + x2.y*wB[u4*4+1] + x2.z*wB[u4*4+2] + x2.w*wB[u4*4+3];
            acc3 += x3.x*wB[u4*4] + x3.y*wB[u4*4+1] + x3.z*wB[u4*4+2] + x3.w*wB[u4*4+3];
        }
    }

    const int n = half * 64 + col;
    lds_p[kseg][0][n] = acc0;
    lds_p[kseg][1][n] = acc1;
    lds_p[kseg][2][n] = acc2;
    lds_p[kseg][3][n] = acc3;
    __syncthreads();

    if (tid < 512) {
        const int t = tid >> 7;
        const int c = tid & 127;
        float v = lds_p[0][t][c] + lds_p[1][t][c] + lds_p[2][t][c] + lds_p[3][t][c];
        const int cc = c & 63;
        if (c < 64) { v += bq[cc]; qws[(size_t)(tok_base + t) * HSc + cc] = v; }
        else        { v += bk[cc]; kws[(size_t)(tok_base + t) * HSc + cc] = v; }
        lds_c[t][c] = v;
    }
    __syncthreads();

    // Phase B: A[t] = q@Wb[0:64]; E[t] = q@Wb[128:192] + k@(Wb[64:128]+Wb[192:256]) + bb
    if (tid < 128) {
        const int t = tid >> 5;
        const int c = tid & 31;
        const int tok = tok_base + t;
        const float* row = lds_c[t];
        if (c < 16) {
            float a = 0.f;
            #pragma unroll 8
            for (int h = 0; h < 64; ++h)
                a += row[h] * Wb[h * OUTc + c];
            Aws[(size_t)tok * OUTc + c] = a;
        } else {
            const int o = c - 16;
            float ev = bb[o];
            #pragma unroll 8
            for (int h = 0; h < 64; ++h) {
                ev += row[h]      * Wb[(128 + h) * OUTc + o];
                ev += row[64 + h] * (Wb[(64 + h) * OUTc + o] + Wb[(192 + h) * OUTc + o]);
            }
            Ews[(size_t)tok * OUTc + o] = ev;
        }
    }
}

// Kernel 2 (unchanged, R6 tiled): Grid (8, 32, 4): x = e-tile (64 e's),
// y = s-tile (16 s's), z = batch. Tiles below diagonal exit early.
// q/A in LDS; k row + E chunk register-resident across 16 s-iterations.
__global__ __launch_bounds__(256) void pair_kernel(
    const float* __restrict__ qws, const float* __restrict__ kws,
    const float* __restrict__ Aws, const float* __restrict__ Ews,
    float* __restrict__ out)
{
    const int j = blockIdx.x;        // e-tile 0..7
    const int i = blockIdx.y;        // s-tile 0..31
    const int b = blockIdx.z;
    if (j < (i >> 2)) return;        // tile entirely below diagonal

    __shared__ alignas(16) float q_tile[16][64];
    __shared__ alignas(16) float A_tile[16][16];

    const int tid = threadIdx.x;
    const int s0 = i * 16;
    const int e0 = j * 64;

    {
        const int r = tid >> 4, c4 = tid & 15;
        ((float4*)q_tile[r])[c4] =
            ((const float4*)(qws + ((size_t)b * Lc + s0 + r) * HSc))[c4];
        if (tid < 64) {
            const int ra = tid >> 2, ca = tid & 3;
            ((float4*)A_tile[ra])[ca] =
                ((const float4*)(Aws + ((size_t)b * Lc + s0 + ra) * OUTc))[ca];
        }
    }
    __syncthreads();

    const int g = tid >> 2;          // group 0..63 -> e_local
    const int l = tid & 3;           // lane in group
    const int e = e0 + g;

    const float4* kk = (const float4*)(kws + ((size_t)b * Lc + e) * HSc);
    const float4 kv0 = kk[l];
    const float4 kv1 = kk[4 + l];
    const float4 kv2 = kk[8 + l];
    const float4 kv3 = kk[12 + l];
    const float4 ev  = ((const float4*)(Ews + ((size_t)b * Lc + e) * OUTc))[l];

    float* ob = out + (size_t)b * Pc * OUTc;

    #pragma unroll 8
    for (int sl = 0; sl < 16; ++sl) {
        const int s = s0 + sl;
        const float4* qq = (const float4*)q_tile[sl];
        const float4 qv0 = qq[l];
        const float4 qv1 = qq[4 + l];
        const float4 qv2 = qq[8 + l];
        const float4 qv3 = qq[12 + l];

        float sc = qv0.x * kv0.x + qv0.y * kv0.y + qv0.z * kv0.z + qv0.w * kv0.w
                 + qv1.x * kv1.x + qv1.y * kv1.y + qv1.z * kv1.z + qv1.w * kv1.w
                 + qv2.x * kv2.x + qv2.y * kv2.y + qv2.z * kv2.z + qv2.w * kv2.w
                 + qv3.x * kv3.x + qv3.y * kv3.y + qv3.z * kv3.z + qv3.w * kv3.w;
        sc += __shfl_xor(sc, 1);
        sc += __shfl_xor(sc, 2);

        if (e >= s) {
            const float4 av = ((const float4*)A_tile[sl])[l];
            const int row = s * (2 * Lc + 1 - s) / 2 + (e - s);
            floatx4 r;
            r.x = av.x + ev.x + sc;
            r.y = av.y + ev.y + sc;
            r.z = av.z + ev.z + sc;
            r.w = av.w + ev.w + sc;
            __builtin_nontemporal_store(r, (floatx4*)(ob + (size_t)row * OUTc) + l);
        }
    }
}

extern "C" void kernel_launch(void* const* d_in, const int* in_sizes, int n_in,
                              void* d_out, int out_size, void* d_ws, size_t ws_size,
                              hipStream_t stream) {
    const float* x  = (const float*)d_in[0];
    const float* Wq = (const float*)d_in[1];
    const float* bq = (const float*)d_in[2];
    const float* Wk = (const float*)d_in[3];
    const float* bk = (const float*)d_in[4];
    const float* Wb = (const float*)d_in[5];
    const float* bb = (const float*)d_in[6];

    float* ws  = (float*)d_ws;
    float* qws = ws;
    float* kws = ws + 131072;
    float* Aws = ws + 262144;
    float* Ews = ws + 294912;

    qk_proj_kernel<<<dim3(512), dim3(512), 0, stream>>>(
        x, Wq, bq, Wk, bk, Wb, bb, qws, kws, Aws, Ews);
    pair_kernel<<<dim3(8, 32, 4), dim3(256), 0, stream>>>(
        qws, kws, Aws, Ews, (float*)d_out);
}

// Round 8
// 99.547 us; speedup vs baseline: 1.1352x; 1.1352x over previous
//
#include <hip/hip_runtime.h>
#include <hip/hip_bf16.h>

// Problem constants (B, L, H, HS, OUT) = (4, 512, 768, 64, 16)
#define Bc   4
#define Lc   512
#define Hc   768
#define HSc  64
#define OUTc 16
#define Pc   131328   // L*(L+1)/2
#define NTOK 2048     // B*L

typedef float  floatx4 __attribute__((ext_vector_type(4)));
typedef short  bf16x8  __attribute__((ext_vector_type(8)));   // 8 bf16 in 4 VGPRs
typedef float  f32x4   __attribute__((ext_vector_type(4)));

// ws layout:
//   floats : q@0 [131072], k@131072 [131072], A@262144 [32768], E@294912 [32768]
//   ushorts @ byte offset 327680*4: xbf [2048*768], Wt [128*768]  (Wt = concat(Wq|Wk)^T)

__device__ __forceinline__ unsigned short f2bf(float f) {
    unsigned int u = __float_as_uint(f);
    return (unsigned short)((u + 0x7FFFu + ((u >> 16) & 1u)) >> 16);   // RNE
}

// Prep: blocks 0..511 convert x to bf16; blocks 512..559 build Wt[n][k] bf16.
__global__ __launch_bounds__(256) void prep_kernel(
    const float* __restrict__ x, const float* __restrict__ Wq,
    const float* __restrict__ Wk,
    unsigned short* __restrict__ xbf, unsigned short* __restrict__ Wt)
{
    const int bx  = blockIdx.x;
    const int tid = threadIdx.x;
    if (bx < 512) {
        // 393216 float4 total = 512 blocks * 256 thr * 3
        const float4* xg = (const float4*)x;
        const int base = bx * 768;
        #pragma unroll
        for (int i = 0; i < 3; ++i) {
            const int idx = base + tid + i * 256;
            const float4 v = xg[idx];
            ushort4 o;
            o.x = f2bf(v.x); o.y = f2bf(v.y); o.z = f2bf(v.z); o.w = f2bf(v.w);
            ((ushort4*)xbf)[idx] = o;
        }
    } else {
        // W transpose tile: k rows [k0, k0+16) x 128 n -> Wt[n][k]
        const int k0 = (bx - 512) * 16;
        __shared__ unsigned short T[128][16];
        const int c  = tid & 127;           // n col
        const int kg = tid >> 7;            // 0..1
        const float* Wsrc = (c < 64) ? Wq : Wk;
        const int cc = c & 63;
        #pragma unroll
        for (int kk = 0; kk < 8; ++kk) {
            const int k = k0 + kg * 8 + kk;
            T[c][kg * 8 + kk] = f2bf(Wsrc[k * HSc + cc]);
        }
        __syncthreads();
        const int n = tid >> 1;
        const int h = tid & 1;
        const unsigned short* src = &T[n][h * 8];
        ushort4* dst = (ushort4*)(Wt + (size_t)n * Hc + k0 + h * 8);
        dst[0] = make_ushort4(src[0], src[1], src[2], src[3]);
        dst[1] = make_ushort4(src[4], src[5], src[6], src[7]);
    }
}

// MFMA GEMM: C[m][n] = x[m][:] . W[:][n], M=2048 N=128 K=768, bf16 in fp32 acc.
// Grid 256 x 256 thr (4 waves). Block bx: mb=bx>>1 (16-token tile), nh=bx&1
// (64-col half). Wave w owns n-tile nb = nh*64 + w*16. No LDS, no barriers:
// a/b fragments stream from L2 (xbf rows / Wt rows, 16B per lane per load),
// fully unrolled K-loop -> compiler vmcnt-pipelines freely.
// Layouts (m89/m91/m120): A[m=lane&15][k=quad*8+j]; B[k=quad*8+j][n=lane&15]
// loaded as Wt rows; D: col=lane&15, row=quad*4+reg.
__global__ __launch_bounds__(256) void gemm_kernel(
    const unsigned short* __restrict__ xbf, const unsigned short* __restrict__ Wt,
    const float* __restrict__ bq, const float* __restrict__ bk,
    float* __restrict__ qws, float* __restrict__ kws)
{
    const int bx   = blockIdx.x;
    const int mb   = bx >> 1;
    const int nh   = bx & 1;
    const int tid  = threadIdx.x;
    const int w    = tid >> 6;
    const int lane = tid & 63;
    const int l15  = lane & 15;
    const int quad = lane >> 4;

    const int m0 = mb * 16;
    const int nb = nh * 64 + w * 16;

    const unsigned short* ap = xbf + (size_t)(m0 + l15) * Hc + quad * 8;
    const unsigned short* bp = Wt  + (size_t)(nb + l15) * Hc + quad * 8;

    f32x4 acc = {0.f, 0.f, 0.f, 0.f};
    #pragma unroll
    for (int k0 = 0; k0 < Hc; k0 += 32) {
        const bf16x8 a = *(const bf16x8*)(ap + k0);
        const bf16x8 b = *(const bf16x8*)(bp + k0);
        acc = __builtin_amdgcn_mfma_f32_16x16x32_bf16(a, b, acc, 0, 0, 0);
    }

    const int  gn   = nb + l15;
    const bool isq  = (gn < 64);          // wave-uniform (nb mult of 16)
    const int  col  = gn & 63;
    const float bias = isq ? bq[col] : bk[col];
    float* dst = isq ? qws : kws;
    #pragma unroll
    for (int r = 0; r < 4; ++r) {
        const int tok = m0 + quad * 4 + r;
        dst[(size_t)tok * HSc + col] = acc[r] + bias;
    }
}

// A/E projections: A[t] = q@Wb[0:64]; E[t] = q@Wb[128:192] + k@(Wb[64:128]+Wb[192:256]) + bb.
// Grid 256 x 256 thr; 8 tokens/block; Wb staged in LDS (16 KB).
__global__ __launch_bounds__(256) void ae_kernel(
    const float* __restrict__ qws, const float* __restrict__ kws,
    const float* __restrict__ Wb, const float* __restrict__ bb,
    float* __restrict__ Aws, float* __restrict__ Ews)
{
    __shared__ float lWb[256 * OUTc];     // 16 KB
    __shared__ float lqk[8][128];
    const int tid = threadIdx.x;
    const int tok_base = blockIdx.x * 8;
    #pragma unroll
    for (int i = 0; i < 16; ++i) lWb[tid + i * 256] = Wb[tid + i * 256];
    for (int i = tid; i < 8 * 128; i += 256) {
        const int t = i >> 7, c = i & 127;
        lqk[t][c] = (c < 64) ? qws[(size_t)(tok_base + t) * HSc + c]
                             : kws[(size_t)(tok_base + t) * HSc + (c - 64)];
    }
    __syncthreads();
    const int t = tid >> 5;
    const int c = tid & 31;
    const int tok = tok_base + t;
    const float* row = lqk[t];
    if (c < 16) {
        float a = 0.f;
        #pragma unroll 8
        for (int h = 0; h < 64; ++h) a += row[h] * lWb[h * OUTc + c];
        Aws[(size_t)tok * OUTc + c] = a;
    } else {
        const int o = c - 16;
        float ev = bb[o];
        #pragma unroll 8
        for (int h = 0; h < 64; ++h) {
            ev += row[h]      * lWb[(128 + h) * OUTc + o];
            ev += row[64 + h] * (lWb[(64 + h) * OUTc + o] + lWb[(192 + h) * OUTc + o]);
        }
        Ews[(size_t)tok * OUTc + o] = ev;
    }
}

// Pair kernel (unchanged R6 tiled): Grid (8, 32, 4): x = e-tile (64 e's),
// y = s-tile (16 s's), z = batch. Tiles below diagonal exit early.
// q/A in LDS; k row + E chunk register-resident across 16 s-iterations.
__global__ __launch_bounds__(256) void pair_kernel(
    const float* __restrict__ qws, const float* __restrict__ kws,
    const float* __restrict__ Aws, const float* __restrict__ Ews,
    float* __restrict__ out)
{
    const int j = blockIdx.x;
    const int i = blockIdx.y;
    const int b = blockIdx.z;
    if (j < (i >> 2)) return;

    __shared__ alignas(16) float q_tile[16][64];
    __shared__ alignas(16) float A_tile[16][16];

    const int tid = threadIdx.x;
    const int s0 = i * 16;
    const int e0 = j * 64;

    {
        const int r = tid >> 4, c4 = tid & 15;
        ((float4*)q_tile[r])[c4] =
            ((const float4*)(qws + ((size_t)b * Lc + s0 + r) * HSc))[c4];
        if (tid < 64) {
            const int ra = tid >> 2, ca = tid & 3;
            ((float4*)A_tile[ra])[ca] =
                ((const float4*)(Aws + ((size_t)b * Lc + s0 + ra) * OUTc))[ca];
        }
    }
    __syncthreads();

    const int g = tid >> 2;
    const int l = tid & 3;
    const int e = e0 + g;

    const float4* kk = (const float4*)(kws + ((size_t)b * Lc + e) * HSc);
    const float4 kv0 = kk[l];
    const float4 kv1 = kk[4 + l];
    const float4 kv2 = kk[8 + l];
    const float4 kv3 = kk[12 + l];
    const float4 ev  = ((const float4*)(Ews + ((size_t)b * Lc + e) * OUTc))[l];

    float* ob = out + (size_t)b * Pc * OUTc;

    #pragma unroll 8
    for (int sl = 0; sl < 16; ++sl) {
        const int s = s0 + sl;
        const float4* qq = (const float4*)q_tile[sl];
        const float4 qv0 = qq[l];
        const float4 qv1 = qq[4 + l];
        const float4 qv2 = qq[8 + l];
        const float4 qv3 = qq[12 + l];

        float sc = qv0.x * kv0.x + qv0.y * kv0.y + qv0.z * kv0.z + qv0.w * kv0.w
                 + qv1.x * kv1.x + qv1.y * kv1.y + qv1.z * kv1.z + qv1.w * kv1.w
                 + qv2.x * kv2.x + qv2.y * kv2.y + qv2.z * kv2.z + qv2.w * kv2.w
                 + qv3.x * kv3.x + qv3.y * kv3.y + qv3.z * kv3.z + qv3.w * kv3.w;
        sc += __shfl_xor(sc, 1);
        sc += __shfl_xor(sc, 2);

        if (e >= s) {
            const float4 av = ((const float4*)A_tile[sl])[l];
            const int row = s * (2 * Lc + 1 - s) / 2 + (e - s);
            floatx4 r;
            r.x = av.x + ev.x + sc;
            r.y = av.y + ev.y + sc;
            r.z = av.z + ev.z + sc;
            r.w = av.w + ev.w + sc;
            __builtin_nontemporal_store(r, (floatx4*)(ob + (size_t)row * OUTc) + l);
        }
    }
}

extern "C" void kernel_launch(void* const* d_in, const int* in_sizes, int n_in,
                              void* d_out, int out_size, void* d_ws, size_t ws_size,
                              hipStream_t stream) {
    const float* x  = (const float*)d_in[0];
    const float* Wq = (const float*)d_in[1];
    const float* bq = (const float*)d_in[2];
    const float* Wk = (const float*)d_in[3];
    const float* bk = (const float*)d_in[4];
    const float* Wb = (const float*)d_in[5];
    const float* bb = (const float*)d_in[6];

    float* ws  = (float*)d_ws;
    float* qws = ws;
    float* kws = ws + 131072;
    float* Aws = ws + 262144;
    float* Ews = ws + 294912;
    unsigned short* xbf = (unsigned short*)(ws + 327680);
    unsigned short* Wt  = xbf + (size_t)NTOK * Hc;

    prep_kernel<<<dim3(560), dim3(256), 0, stream>>>(x, Wq, Wk, xbf, Wt);
    gemm_kernel<<<dim3(256), dim3(256), 0, stream>>>(xbf, Wt, bq, bk, qws, kws);
    ae_kernel<<<dim3(256), dim3(256), 0, stream>>>(qws, kws, Wb, bb, Aws, Ews);
    pair_kernel<<<dim3(8, 32, 4), dim3(256), 0, stream>>>(
        qws, kws, Aws, Ews, (float*)d_out);
}